// Round 9
// baseline (548.476 us; speedup 1.0000x reference)
//
#include <hip/hip_runtime.h>

// LoRA forward: out = (h @ B^T) @ A^T, h: (16384, 4096) f32, rank 16.
// R9: two-kernel split, K1 with NO LDS staging.
//  K1: 256 blocks x 1024 thr. Wave w owns d-window [w*256,(w+1)*256); lane l
//      owns 4 floats of it. B fragment (16 x float4 = 64 VGPR) loaded once.
//      64 rows/block streamed as direct coalesced 1-KB wave loads (2-row
//      prefetch, no barriers). Per row: 16 dot4 + 17-shuffle fold reduction
//      -> lane 4r holds hr-partial[r] -> 4-B LDS write. One barrier, then
//      1024-thr reduce of [64][16][16] partials -> hr (d_ws).
//  K2: out = hr @ A^T. A fragment in VGPRs, uniform hr loads, NT stores.

constexpr int  D  = 4096;
constexpr int  RK = 16;
constexpr long M  = 16384;

typedef float f32x4 __attribute__((ext_vector_type(4)));

__device__ __forceinline__ float dot4(float4 a, float4 b) {
  return a.x * b.x + a.y * b.y + a.z * b.z + a.w * b.w;
}

// ---------------------------------------------------------------- K1 -------
__device__ __forceinline__ void rowwork(float4 h4, const float4* bfrag,
                                        int l, float* dst16) {
  float acc[RK];
#pragma unroll
  for (int r = 0; r < RK; ++r) acc[r] = dot4(h4, bfrag[r]);
  // fold reduction: halve value count over lane bits 5,4,3,2
#pragma unroll
  for (int step = 0; step < 4; ++step) {
    const int mask = 32 >> step;   // 32,16,8,4
    const int half = 8 >> step;    // 8,4,2,1
    const bool up = (l & mask) != 0;
#pragma unroll
    for (int i = 0; i < half; ++i) {
      const float keep = up ? acc[i + half] : acc[i];
      const float send = up ? acc[i] : acc[i + half];
      acc[i] = keep + __shfl_xor(send, mask, 64);
    }
  }
  // now acc[0] holds rank r = (l>>2)&15, summed over lane bits 5..2;
  // finish sum over lane bits 1,0:
  acc[0] += __shfl_xor(acc[0], 2, 64);
  acc[0] += __shfl_xor(acc[0], 1, 64);
  if ((l & 3) == 0) dst16[l >> 2] = acc[0];
}

__global__ __launch_bounds__(1024) void lora_k1(
    const float* __restrict__ h,
    const float* __restrict__ matB,    // (RK, D) row-major
    float* __restrict__ hr) {          // (M, RK)
  __shared__ float part[64][16][RK];   // 64 KB [row][wave][r]

  const int tid = threadIdx.x;
  const int w   = tid >> 6;            // wave id 0..15 (d-window)
  const int l   = tid & 63;
  const long row0 = (long)blockIdx.x * 64;

  // B fragment: 16 x float4, loaded once (L2/L3-hot; same for all blocks)
  float4 bfrag[RK];
#pragma unroll
  for (int r = 0; r < RK; ++r)
    bfrag[r] = *reinterpret_cast<const float4*>(matB + (long)r * D +
                                                w * 256 + l * 4);

  const float* hw = h + w * 256 + l * 4;
  auto LD = [&](int row) {
    return *reinterpret_cast<const float4*>(hw + (row0 + row) * (long)D);
  };

  float4 c0 = LD(0), c1 = LD(1);
#pragma unroll 1
  for (int row = 0; row < 64; row += 2) {
    const int p2 = (row + 2 < 64) ? row + 2 : 63;   // clamped prefetch
    const int p3 = (row + 3 < 64) ? row + 3 : 63;
    float4 n0 = LD(p2);
    float4 n1 = LD(p3);
    rowwork(c0, bfrag, l, &part[row][w][0]);
    rowwork(c1, bfrag, l, &part[row + 1][w][0]);
    c0 = n0;
    c1 = n1;
  }
  __syncthreads();

  // 1024-thr reduce: thread -> (row = tid>>4, r = tid&15)
  {
    const int row = tid >> 4, r = tid & 15;
    float s = 0.f;
#pragma unroll
    for (int w2 = 0; w2 < 16; ++w2) s += part[row][w2][r];
    hr[(row0 + row) * RK + r] = s;   // coalesced 4-KB block write; L2-hot
  }
}

// ---------------------------------------------------------------- K2 -------
__global__ __launch_bounds__(256) void lora_k2(
    const float* __restrict__ hr,     // (M, RK)
    const float* __restrict__ matA,   // (D, RK) row-major
    float* __restrict__ out) {
  const int tid = threadIdx.x;
  const int cs  = blockIdx.x & 3;          // column slice (1024 cols)
  const long row0 = (long)(blockIdx.x >> 2) * 64;
  const int c0 = cs * 1024 + tid * 4;      // 4 contiguous cols per thread

  float4 a[4][4];  // A rows for my 4 cols: 64 VGPRs, reused 64x
#pragma unroll
  for (int j = 0; j < 4; ++j)
#pragma unroll
    for (int q = 0; q < 4; ++q)
      a[j][q] = *reinterpret_cast<const float4*>(
          matA + (long)(c0 + j) * RK + q * 4);

#pragma unroll 4
  for (int rr = 0; rr < 64; ++rr) {
    const float4* hv =
        reinterpret_cast<const float4*>(hr + (row0 + rr) * RK);  // uniform
    const float4 h0 = hv[0], h1 = hv[1], h2 = hv[2], h3 = hv[3];
    f32x4 o;
    o.x = dot4(h0, a[0][0]) + dot4(h1, a[0][1]) + dot4(h2, a[0][2]) +
          dot4(h3, a[0][3]);
    o.y = dot4(h0, a[1][0]) + dot4(h1, a[1][1]) + dot4(h2, a[1][2]) +
          dot4(h3, a[1][3]);
    o.z = dot4(h0, a[2][0]) + dot4(h1, a[2][1]) + dot4(h2, a[2][2]) +
          dot4(h3, a[2][3]);
    o.w = dot4(h0, a[3][0]) + dot4(h1, a[3][1]) + dot4(h2, a[3][2]) +
          dot4(h3, a[3][3]);
    __builtin_nontemporal_store(
        o, reinterpret_cast<f32x4*>(out + (row0 + rr) * (long)D + c0));
  }
}

extern "C" void kernel_launch(void* const* d_in, const int* in_sizes, int n_in,
                              void* d_out, int out_size, void* d_ws,
                              size_t ws_size, hipStream_t stream) {
  const float* h    = (const float*)d_in[0];
  const float* matA = (const float*)d_in[1];
  const float* matB = (const float*)d_in[2];
  float* out        = (float*)d_out;
  float* hr         = (float*)d_ws;   // M * RK * 4 = 1 MiB scratch

  hipLaunchKernelGGL(lora_k1, dim3((int)(M / 64)), dim3(1024), 0, stream,
                     h, matB, hr);
  hipLaunchKernelGGL(lora_k2, dim3((int)(M / 64) * 4), dim3(256), 0, stream,
                     hr, matA, out);
}

// Round 10
// 99.855 us; speedup vs baseline: 5.4927x; 5.4927x over previous
//
#include <hip/hip_runtime.h>

// LoRA forward: out = (h @ B^T) @ A^T, h: (16384, 4096) f32, rank 16.
// R10: K1 uses bf16 MFMA (16x16x32) so the cross-lane d-reduction happens in
// the matrix pipe, not VALU/shuffles. Wave-private LDS staging + counted
// vmcnt => NO barriers in the k-loop. K2 = proven NT-store write streamer.

constexpr int  D  = 4096;
constexpr int  RK = 16;
constexpr long M  = 16384;

typedef float f32x4 __attribute__((ext_vector_type(4)));
typedef short bf16x8 __attribute__((ext_vector_type(8)));
typedef int   i32x4 __attribute__((ext_vector_type(4)));

__device__ __forceinline__ void gload_lds16(const float* src, float* ldsdst) {
  __builtin_amdgcn_global_load_lds(
      (const __attribute__((address_space(1))) void*)src,
      (__attribute__((address_space(3))) void*)ldsdst, 16, 0, 0);
}

__device__ __forceinline__ float dot4(float4 a, float4 b) {
  return a.x * b.x + a.y * b.y + a.z * b.z + a.w * b.w;
}

__device__ __forceinline__ unsigned cvt_pk_bf16(float lo, float hi) {
  unsigned r;
  asm("v_cvt_pk_bf16_f32 %0, %1, %2" : "=v"(r) : "v"(lo), "v"(hi));
  return r;
}

__device__ __forceinline__ bf16x8 to_bf16x8(float4 a, float4 b) {
  i32x4 u;
  u.x = (int)cvt_pk_bf16(a.x, a.y);
  u.y = (int)cvt_pk_bf16(a.z, a.w);
  u.z = (int)cvt_pk_bf16(b.x, b.y);
  u.w = (int)cvt_pk_bf16(b.z, b.w);
  return __builtin_bit_cast(bf16x8, u);
}

// ---------------------------------------------------------------- K1 -------
// Block = 32 rows. Wave w: row-tile t=w&1 (16 rows), k-half q=w>>1 (2048).
// 64 chunks of K=32 per wave; 1 MFMA per chunk; acc = 4 f32/lane.
constexpr int KC   = 32;            // k per chunk (one MFMA)
constexpr int NCH1 = 2048 / KC;     // 64 chunks per wave

__global__ __launch_bounds__(256, 4) void lora_k1(
    const float* __restrict__ h,
    const float* __restrict__ matB,   // (RK, D) row-major
    float* __restrict__ hr) {         // (M, RK)
  __shared__ float sH[4][4][16][KC];  // [wave][ringbuf][row][k] 32 KB
  __shared__ float part[4][16][RK];   // [wave][row][rank]       4 KB

  const int tid = threadIdx.x;
  const int wu  = __builtin_amdgcn_readfirstlane(tid >> 6);  // wave 0..3
  const int l   = tid & 63;
  const int t   = wu & 1;             // row-tile
  const int q   = wu >> 1;            // k-half
  const long rowt = (long)blockIdx.x * 32 + t * 16;
  const int  k0   = q * 2048;

  // ---- stage chunk c into ring buf b: 2 x 1-KB wave loads ----------------
  // load ld covers LDS rows ld*8..+8 linearly (lane l -> row ld*8+(l>>3),
  // 16-B slot l&7). XOR swizzle lives in the SOURCE slot: sd ^ (R&7).
  auto STAGE = [&](int b, int c) {
#pragma unroll
    for (int ld = 0; ld < 2; ++ld) {
      const int R  = ld * 8 + (l >> 3);
      const int sd = l & 7;
      const float* src =
          h + (rowt + R) * (long)D + k0 + c * KC + ((sd ^ (R & 7)) * 4);
      gload_lds16(src, &sH[wu][b][ld * 8][0]);
    }
  };
  // ---- B fragment f32 prefetch for chunk c: lane -> rank l&15, k (l>>4)*8
  auto BLOAD = [&](int c, float4& b0, float4& b1) {
    const float* bp = matB + (long)(l & 15) * D + k0 + c * KC + (l >> 4) * 8;
    b0 = *reinterpret_cast<const float4*>(bp);
    b1 = *reinterpret_cast<const float4*>(bp + 4);
  };

  f32x4 acc = {0.f, 0.f, 0.f, 0.f};
  float4 bc0, bc1, bn0, bn1;

  // prologue: queue = h(0):2, B(0):2, h(1):2
  STAGE(0, 0);
  BLOAD(0, bc0, bc1);
  STAGE(1, 1);

#pragma unroll 1
  for (int c = 0; c < NCH1; ++c) {
    const int cb = (c + 1 < NCH1) ? c + 1 : NCH1 - 1;   // clamped prefetch
    const int cs = (c + 2 < NCH1) ? c + 2 : NCH1 - 1;
    BLOAD(cb, bn0, bn1);            // B(c+1): 2 loads
    STAGE((c + 2) & 3, cs);         // h(c+2): 2 loads
    // queue: h(c),B(c),h(c+1),B(c+1),h(c+2) = 10 outstanding.
    // vmcnt(6) retires h(c),B(c); keeps 4 KB of h + next B in flight.
    asm volatile("s_waitcnt vmcnt(6)" ::: "memory");
    __builtin_amdgcn_sched_barrier(0);

    // A fragment: row r=l&15, global slots sj,sj+1 (sj=(l>>4)*2), deswizzled
    const float* abase = &sH[wu][c & 3][l & 15][0];
    const int sj = (l >> 4) * 2, r7 = l & 7;
    const float4 a0 =
        *reinterpret_cast<const float4*>(abase + ((sj ^ r7) * 4));
    const float4 a1 =
        *reinterpret_cast<const float4*>(abase + (((sj + 1) ^ r7) * 4));

    const bf16x8 af = to_bf16x8(a0, a1);
    const bf16x8 bf = to_bf16x8(bc0, bc1);
    acc = __builtin_amdgcn_mfma_f32_16x16x32_bf16(af, bf, acc, 0, 0, 0);

    bc0 = bn0;
    bc1 = bn1;
  }

  asm volatile("s_waitcnt vmcnt(0)" ::: "memory");
  // C/D layout: col(rank) = l&15, row = (l>>4)*4 + j
#pragma unroll
  for (int j = 0; j < 4; ++j) part[wu][(l >> 4) * 4 + j][l & 15] = acc[j];
  __syncthreads();

  // tile0 = waves {0,2}, tile1 = waves {1,3}; write hr coalesced
  {
    const long rbase = (long)blockIdx.x * 32;
#pragma unroll
    for (int e = tid; e < 512; e += 256) {
      const int row = e >> 4, rk = e & 15, tl = row >> 4;
      const float s = part[tl][row & 15][rk] + part[tl + 2][row & 15][rk];
      hr[(rbase + row) * RK + rk] = s;
    }
  }
}

// ---------------------------------------------------------------- K2 -------
__global__ __launch_bounds__(256) void lora_k2(
    const float* __restrict__ hr,     // (M, RK)
    const float* __restrict__ matA,   // (D, RK) row-major
    float* __restrict__ out) {
  const int tid = threadIdx.x;
  const int cs  = blockIdx.x & 3;          // column slice (1024 cols)
  const long row0 = (long)(blockIdx.x >> 2) * 64;
  const int c0 = cs * 1024 + tid * 4;      // 4 contiguous cols per thread

  float4 a[4][4];  // A rows for my 4 cols: 64 VGPRs, reused 64x
#pragma unroll
  for (int j = 0; j < 4; ++j)
#pragma unroll
    for (int qq = 0; qq < 4; ++qq)
      a[j][qq] = *reinterpret_cast<const float4*>(
          matA + (long)(c0 + j) * RK + qq * 4);

#pragma unroll 4
  for (int rr = 0; rr < 64; ++rr) {
    const float4* hv =
        reinterpret_cast<const float4*>(hr + (row0 + rr) * RK);  // uniform
    const float4 h0 = hv[0], h1 = hv[1], h2 = hv[2], h3 = hv[3];
    f32x4 o;
    o.x = dot4(h0, a[0][0]) + dot4(h1, a[0][1]) + dot4(h2, a[0][2]) +
          dot4(h3, a[0][3]);
    o.y = dot4(h0, a[1][0]) + dot4(h1, a[1][1]) + dot4(h2, a[1][2]) +
          dot4(h3, a[1][3]);
    o.z = dot4(h0, a[2][0]) + dot4(h1, a[2][1]) + dot4(h2, a[2][2]) +
          dot4(h3, a[2][3]);
    o.w = dot4(h0, a[3][0]) + dot4(h1, a[3][1]) + dot4(h2, a[3][2]) +
          dot4(h3, a[3][3]);
    __builtin_nontemporal_store(
        o, reinterpret_cast<f32x4*>(out + (row0 + rr) * (long)D + c0));
  }
}

extern "C" void kernel_launch(void* const* d_in, const int* in_sizes, int n_in,
                              void* d_out, int out_size, void* d_ws,
                              size_t ws_size, hipStream_t stream) {
  const float* h    = (const float*)d_in[0];
  const float* matA = (const float*)d_in[1];
  const float* matB = (const float*)d_in[2];
  float* out        = (float*)d_out;
  float* hr         = (float*)d_ws;   // M * RK * 4 = 1 MiB scratch

  hipLaunchKernelGGL(lora_k1, dim3((int)(M / 32)), dim3(256), 0, stream,
                     h, matB, hr);
  hipLaunchKernelGGL(lora_k2, dim3((int)(M / 64) * 4), dim3(256), 0, stream,
                     hr, matA, out);
}